// Round 5
// baseline (205.387 us; speedup 1.0000x reference)
//
#include <hip/hip_runtime.h>
#include <type_traits>

#define NODE 400
#define POP 3
#define TRS 40
#define STEPS 10
#define DMAX 500
#define OUT 64
#define DT 0.1f
#define JPL 7           // ceil(NODE/64) j-indices per lane
#define WSTR 512        // per-stream W bin stride (delta in [0,511])
#define NTOT (NODE * NODE)

__device__ __forceinline__ float relu_(float x) { return x > 0.f ? x : 0.f; }
__device__ __forceinline__ float rcp_(float x) { return __builtin_amdgcn_rcpf(x); }
__device__ __forceinline__ float rlane_(float v, int l) {
  return __builtin_bit_cast(float, __builtin_amdgcn_readlane(__builtin_bit_cast(int, v), l));
}
__device__ __forceinline__ float rfl_(float v) {
  return __builtin_bit_cast(float, __builtin_amdgcn_readfirstlane(__builtin_bit_cast(int, v)));
}

template <int CTRL>
__device__ __forceinline__ float dpp_mov(float x) {
  int r = __builtin_amdgcn_update_dpp(0, __builtin_bit_cast(int, x), CTRL,
                                      0xf, 0xf, true);
  return __builtin_bit_cast(float, r);
}
template <int CTRL>
__device__ __forceinline__ int dpp_movi(int x) {
  return __builtin_amdgcn_update_dpp(0, x, CTRL, 0xf, 0xf, true);
}
// wave_rol:1 (0x134): lane n receives lane (n+1)&63's value.
// (If direction proves wrong, switch to 0x13C wave_ror:1.)
__device__ __forceinline__ float rol1_(float x) { return dpp_mov<0x134>(x); }

__device__ __forceinline__ void wave_reduce3(float& a, float& b, float& c) {
  a += dpp_mov<0x111>(a); b += dpp_mov<0x111>(b); c += dpp_mov<0x111>(c);
  a += dpp_mov<0x112>(a); b += dpp_mov<0x112>(b); c += dpp_mov<0x112>(c);
  a += dpp_mov<0x114>(a); b += dpp_mov<0x114>(b); c += dpp_mov<0x114>(c);
  a += dpp_mov<0x118>(a); b += dpp_mov<0x118>(b); c += dpp_mov<0x118>(c);
  a += dpp_mov<0x142>(a); b += dpp_mov<0x142>(b); c += dpp_mov<0x142>(c);
  a += dpp_mov<0x143>(a); b += dpp_mov<0x143>(b); c += dpp_mov<0x143>(c);
  a = rlane_(a, 63); b = rlane_(b, 63); c = rlane_(c, 63);
}
__device__ __forceinline__ float wave_reduce1(float a) {
  a += dpp_mov<0x111>(a);
  a += dpp_mov<0x112>(a);
  a += dpp_mov<0x114>(a);
  a += dpp_mov<0x118>(a);
  a += dpp_mov<0x142>(a);
  a += dpp_mov<0x143>(a);
  return rlane_(a, 63);
}
__device__ __forceinline__ int wave_max_int(int x) {
  x = max(x, dpp_movi<0x111>(x));
  x = max(x, dpp_movi<0x112>(x));
  x = max(x, dpp_movi<0x114>(x));
  x = max(x, dpp_movi<0x118>(x));
  x = max(x, dpp_movi<0x142>(x));
  x = max(x, dpp_movi<0x143>(x));
  return __builtin_amdgcn_readlane(x, 63);
}

// ---------------------------------------------------------------------------
// ONE fused kernel: [ssq partials] -> bar0 -> [sim per node] -> bar1 -> [eeg].
// 400 blocks x 64 threads, ~9.7KB LDS, VGPR~128 -> all blocks co-resident,
// so device-scope atomic spin barriers are safe.
// Rotating-partial scatter: at step t, lane l bank k holds P for step t+l+64k.
// Harvest = readfirstlane; rotate = wave_rol:1 + lane63 bank-shift; scatter
// weights are per-lane constants W[l+64k] (raw; norms folded into scalars).
// ---------------------------------------------------------------------------
__global__ __launch_bounds__(64) void fused_kernel(
    const float* __restrict__ external, const float* __restrict__ hx,
    const float* __restrict__ hE, const float* __restrict__ sc,
    const float* __restrict__ dist, const float* __restrict__ wbb,
    const float* __restrict__ wff, const float* __restrict__ wll,
    const float* __restrict__ lm, const float* __restrict__ theta,
    unsigned* __restrict__ bar, float* __restrict__ part,
    float* __restrict__ vsnap, float* __restrict__ out) {
  const int node = blockIdx.x;
  const int lane = threadIdx.x;

  __shared__ float Wall[3 * WSTR];   // Wl | Wf | Wb raw delay bins
  __shared__ float hE_lds[DMAX];
  __shared__ float u_lds[STEPS * TRS];

  // --- parameters ---
  const float VL = relu_(theta[0]), VI = relu_(theta[1]);
  const float VE = relu_(theta[2]), VNMDA = relu_(theta[3]);
  const float alpha_mg = relu_(theta[4]), VR = relu_(theta[5]);
  const float pi_sigma = relu_(theta[6]);
  const float gLp = relu_(theta[7]), Cc = relu_(theta[8]), kappa = relu_(theta[9]);
  const float g_gE = relu_(theta[10]), g_gE_sc = relu_(theta[11]);
  const float g_gI = relu_(theta[12]), g_gI_sc = relu_(theta[13]);
  const float g_gN = relu_(theta[14]), g_gN_sc = relu_(theta[15]);
  const float g_k = relu_(theta[16]);
  const float y0v = theta[19];
  const float mu = 0.1f + relu_(theta[20]);
  const float uk = relu_(theta[21]) * theta[23];
  const float cy0 = theta[22];
  const float g_l = relu_(theta[24]), g_f = relu_(theta[25]), g_b = relu_(theta[26]);
  const float DTC = DT / Cc;
  const float dk = DT * kappa;
  const float nps = -pi_sigma, psVR = pi_sigma * VR;
  const float nam = -alpha_mg;
  const float dk1 = 1.f - dk;
  const float gLVL = gLp * VL;

  // --- stage LDS (single wave: program order; no barriers needed) ---
  for (int k = lane; k < 3 * WSTR; k += 64) Wall[k] = 0.f;
  for (int d = lane; d < DMAX; d += 64) hE_lds[d] = hE[node * DMAX + d];
  const float ukdk = dk * uk;
  for (int t = lane; t < STEPS * TRS; t += 64)
    u_lds[t] = ukdk * external[node * STEPS * TRS + t];

  // --- phase 1: ssq partial over grid-stride slice; signal bar[0] ---
  {
    float eb = 0.f, ef = 0.f, el = 0.f;
    for (int idx = node * 64 + lane; idx < NTOT; idx += NODE * 64) {
      int i = idx / NODE, j = idx - i * NODE;
      int ji = j * NODE + i;
      float scij = sc[idx];
      float b = __expf(wbb[idx]) * scij;
      float f = __expf(wff[idx]) * scij;
      float l = 0.5f * (__expf(wll[idx]) * scij + __expf(wll[ji]) * sc[ji]);
      eb = fmaf(b, b, eb); ef = fmaf(f, f, ef); el = fmaf(l, l, el);
    }
    wave_reduce3(eb, ef, el);
    if (lane == 0) {
      part[node] = eb; part[NODE + node] = ef; part[2 * NODE + node] = el;
    }
    __threadfence();
    if (lane == 0) atomicAdd(&bar[0], 1u);
  }

  // --- bin RAW weights by delay (LDS float atomics); raw row sums; maxd ---
  float rl = 0.f, rf = 0.f, rb = 0.f;
  int mymax = 0;
#pragma unroll
  for (int kj = 0; kj < JPL; ++kj) {
    int j = lane + kj * 64;
    if (j < NODE) {
      int ij = node * NODE + j;
      int ji = j * NODE + node;
      float scij = sc[ij];
      float vb = __expf(wbb[ij]) * scij;
      float vf = __expf(wff[ij]) * scij;
      float vl = 0.5f * (__expf(wll[ij]) * scij + __expf(wll[ji]) * sc[ji]);
      int dd = (int)(dist[ij] / mu);
      dd = min(max(dd, 0), DMAX - 1);
      atomicAdd(&Wall[dd], vl);
      atomicAdd(&Wall[WSTR + dd], vf);
      atomicAdd(&Wall[2 * WSTR + dd], vb);
      rl += vl; rf += vf; rb += vb;
      mymax = max(mymax, dd);
    }
  }
  wave_reduce3(rl, rf, rb);            // raw row sums
  const int maxd = wave_max_int(mymax);
  const int nb = (maxd >> 6) + 1;

  // --- initial state (replicated across lanes) ---
  const int hb = node * POP * 4;
  float V0 = hx[hb + 0], V1 = hx[hb + 4], V2 = hx[hb + 8];
  float E0 = hx[hb + 1], E1 = hx[hb + 5], E2 = hx[hb + 9];
  float I0 = hx[hb + 2], I1 = hx[hb + 6], I2 = hx[hb + 10];
  float N0 = hx[hb + 3], N1 = hx[hb + 7], N2 = hx[hb + 11];

  auto core = [&](auto nbtag) {
    constexpr int NB = decltype(nbtag)::value;
    // per-lane constant scatter weights (raw): delta = lane + 64k
    float wsl[NB], wsf[NB], wsb[NB];
#pragma unroll
    for (int k = 0; k < NB; ++k) {
      int d = lane + (k << 6);
      wsl[k] = Wall[d]; wsf[k] = Wall[WSTR + d]; wsb[k] = Wall[2 * WSTR + d];
    }

    // prologue: P(T) = sum_m W[T+m]*hE[m], T = lane+64k (raw weights)
    float Pl[NB], Pf[NB], Pb[NB];
#pragma unroll
    for (int k = 0; k < NB; ++k) { Pl[k] = 0.f; Pf[k] = 0.f; Pb[k] = 0.f; }
    for (int m = 0; m <= maxd; ++m) {
      float h = hE_lds[m];
#pragma unroll
      for (int k = 0; k < NB; ++k) {
        int d = lane + (k << 6) + m;
        if constexpr (NB > 2) d = min(d, WSTR - 1);  // W[500..511]==0
        Pl[k] = fmaf(Wall[d], h, Pl[k]);
        Pf[k] = fmaf(Wall[WSTR + d], h, Pf[k]);
        Pb[k] = fmaf(Wall[2 * WSTR + d], h, Pb[k]);
      }
    }

    // --- wait for global ssq, fold norms into scalar constants ---
    while (__hip_atomic_load(&bar[0], __ATOMIC_ACQUIRE,
                             __HIP_MEMORY_SCOPE_AGENT) < (unsigned)NODE)
      __builtin_amdgcn_s_sleep(2);
    __threadfence();
    float sb = 0.f, sf = 0.f, sl = 0.f;
#pragma unroll
    for (int jj = 0; jj < JPL; ++jj) {
      int i = lane + (jj << 6);
      if (i < NODE) {
        sb += part[i]; sf += part[NODE + i]; sl += part[2 * NODE + i];
      }
    }
    wave_reduce3(sb, sf, sl);
    const float inv_nb_ = 1.f / sqrtf(sb);
    const float inv_nf_ = 1.f / sqrtf(sf);
    const float inv_nl_ = 1.f / sqrtf(sl);
    // folded per-step constants (norms applied here, not to the bins)
    const float cA2 = dk * g_l * inv_nl_;           // * raw al
    const float cF2 = dk * g_f * inv_nf_;           // * raw af
    const float cB2 = dk * g_b * inv_nb_;           // * raw ab
    const float rs_l = inv_nl_ * rl, rs_f = inv_nf_ * rf, rs_b = inv_nb_ * rb;
    const float cE0s2 = dk * g_gE - dk * g_l * rs_l;
    const float cN0s2 = dk * g_gN - dk * g_l * rs_l;
    const float cE1s = -(dk * g_b) * rs_b;
    const float cE2s = -(dk * g_f) * rs_f;
    const float cE1e = dk * g_gE_sc, cE2e = dk * g_k;
    const float cI0 = dk * g_gI, cI1 = dk * g_gI_sc;
    const float cN1 = dk * g_gN_sc, cN2 = dk * g_gN;

    const bool is63 = (lane == 63);

    // --- main loop: 400 steps ---
    for (int tr = 0; tr < TRS; ++tr) {
      float u_tr = (lane < STEPS) ? u_lds[lane * TRS + tr] : 0.f;
#pragma unroll
      for (int st = 0; st < STEPS; ++st) {
        // 1) harvest this step's totals (lane0 bank0)
        float alr = rfl_(Pl[0]);
        float afr = rfl_(Pf[0]);
        float abr = rfl_(Pb[0]);

        // 2) rotate partials: lane l <- lane l+1; lane63 pulls next bank
        {
          float r[NB];
#pragma unroll
          for (int k = 0; k < NB; ++k) r[k] = rol1_(Pl[k]);
#pragma unroll
          for (int k = 0; k < NB - 1; ++k) Pl[k] = is63 ? r[k + 1] : r[k];
          Pl[NB - 1] = is63 ? 0.f : r[NB - 1];
#pragma unroll
          for (int k = 0; k < NB; ++k) r[k] = rol1_(Pf[k]);
#pragma unroll
          for (int k = 0; k < NB - 1; ++k) Pf[k] = is63 ? r[k + 1] : r[k];
          Pf[NB - 1] = is63 ? 0.f : r[NB - 1];
#pragma unroll
          for (int k = 0; k < NB; ++k) r[k] = rol1_(Pb[k]);
#pragma unroll
          for (int k = 0; k < NB - 1; ++k) Pb[k] = is63 ? r[k + 1] : r[k];
          Pb[NB - 1] = is63 ? 0.f : r[NB - 1];
        }

        // 3) dynamics (replicated)
        float sE = rcp_(1.f + __expf(fmaf(nps, V0, psVR)));
        float sI = rcp_(1.f + __expf(fmaf(nps, V1, psVR)));
        float sP = rcp_(1.f + __expf(fmaf(nps, V2, psVR)));
        float m0 = rcp_(fmaf(0.2f, __expf(nam * V0), 1.f));
        float m1 = rcp_(fmaf(0.2f, __expf(nam * V1), 1.f));
        float m2 = rcp_(fmaf(0.2f, __expf(nam * V2), 1.f));
        float U = rlane_(u_tr, st);          // pre-scaled by dk*uk

        float t1 = cA2 * alr, t2 = cF2 * afr, t3 = cB2 * abr;
        float nE0 = fmaf(dk1, E0, fmaf(cE0s2, sP, t1 + U));
        float nE1 = fmaf(dk1, E1, fmaf(cE1e, sE, fmaf(cE1s, sP, t3)));
        float nE2 = fmaf(dk1, E2, fmaf(cE2e, sE, fmaf(cE2s, sP, t2 + U)));
        float pI = cI0 * sI;
        float nI0 = fmaf(dk1, I0, pI);
        float nI1 = fmaf(dk1, I1, cI1 * sI);
        float nI2 = fmaf(dk1, I2, pI);
        float nN0 = fmaf(dk1, N0, fmaf(cN0s2, sP, t1));
        float nN1 = fmaf(dk1, N1, cN1 * sE);
        float nN2 = fmaf(dk1, N2, cN2 * sE);

        float Nm0 = N0 * m0, Nm1 = N1 * m1, Nm2 = N2 * m2;
        float R0 = fmaf(E0, VE, fmaf(Nm0, VNMDA, fmaf(I0, -VI, -gLVL)));
        float R1 = fmaf(E1, VE, fmaf(Nm1, VNMDA, fmaf(I1, -VI, -gLVL)));
        float R2 = fmaf(E2, VE, fmaf(Nm2, VNMDA, fmaf(I2, -VI, -gLVL)));
        float S0 = gLp + E0 + I0 + Nm0;
        float S1 = gLp + E1 + I1 + Nm1;
        float S2 = gLp + E2 + I2 + Nm2;
        V0 = fmaf(DTC, fmaf(-S0, V0, R0), V0);
        V1 = fmaf(DTC, fmaf(-S1, V1, R1), V1);
        V2 = fmaf(DTC, fmaf(-S2, V2, R2), V2);
        E0 = nE0; E1 = nE1; E2 = nE2;
        I0 = nI0; I1 = nI1; I2 = nI2;
        N0 = nN0; N1 = nN1; N2 = nN2;

        // 4) scatter s(t) with constant per-lane weights (delta = lane+64k)
#pragma unroll
        for (int k = 0; k < NB; ++k) {
          Pl[k] = fmaf(wsl[k], sP, Pl[k]);
          Pf[k] = fmaf(wsf[k], sP, Pf[k]);
          Pb[k] = fmaf(wsb[k], sP, Pb[k]);
        }
      }
      if (lane == 0) vsnap[tr * NODE + node] = V2;
    }
  };

  if (nb <= 2) core(std::integral_constant<int, 2>{});
  else         core(std::integral_constant<int, 8>{});

  // --- phase 3: eeg readout (blocks 0..TRS-1), after all sims done ---
  __threadfence();
  if (lane == 0) atomicAdd(&bar[1], 1u);
  if (node < TRS) {
    while (__hip_atomic_load(&bar[1], __ATOMIC_ACQUIRE,
                             __HIP_MEMORY_SCOPE_AGENT) < (unsigned)NODE)
      __builtin_amdgcn_s_sleep(2);
    __threadfence();
    const float* vs = vsnap + node * NODE;
    const float* lr = lm + lane * NODE;
    float d0 = 0.f, d1 = 0.f, d2 = 0.f, d3 = 0.f;
    for (int n = 0; n < NODE; n += 4) {
      d0 = fmaf(lr[n], vs[n], d0);
      d1 = fmaf(lr[n + 1], vs[n + 1], d1);
      d2 = fmaf(lr[n + 2], vs[n + 2], d2);
      d3 = fmaf(lr[n + 3], vs[n + 3], d3);
    }
    float dot = (d0 + d1) + (d2 + d3);
    float tot = wave_reduce1(dot);       // sum over o (lanes)
    // lm_d @ v = dot_o - mean_o(dot_o)
    out[node * OUT + lane] = fmaf(cy0, dot - tot * (1.f / OUT), -y0v);
  }
}

extern "C" void kernel_launch(void* const* d_in, const int* in_sizes, int n_in,
                              void* d_out, int out_size, void* d_ws, size_t ws_size,
                              hipStream_t stream) {
  const float* external = (const float*)d_in[0];
  const float* hx       = (const float*)d_in[1];
  const float* hE       = (const float*)d_in[2];
  const float* sc       = (const float*)d_in[3];
  const float* dist     = (const float*)d_in[4];
  const float* wbb      = (const float*)d_in[5];
  const float* wff      = (const float*)d_in[6];
  const float* wll      = (const float*)d_in[7];
  const float* lm       = (const float*)d_in[8];
  const float* theta    = (const float*)d_in[9];
  float* out = (float*)d_out;

  unsigned* bar = (unsigned*)d_ws;                 // [0],[1] barrier counters
  float* part  = (float*)d_ws + 4;                 // 3*NODE ssq partials
  float* vsnap = part + 3 * NODE;                  // TRS*NODE V2 snapshots

  hipMemsetAsync(d_ws, 0, 16, stream);             // zero the two counters
  fused_kernel<<<NODE, 64, 0, stream>>>(external, hx, hE, sc, dist, wbb, wff,
                                        wll, lm, theta, bar, part, vsnap, out);
}